// Round 5
// baseline (14060.762 us; speedup 1.0000x reference)
//
#include <hip/hip_runtime.h>

// PBRNN LSTM: B=64, S=512, D=544, H=1024. out = [h_n; c_n] fp32 [2,64,1024].
//
// Round 9 (resubmit — R4 bench was a GPUAcquisitionTimeout, no data):
// XCD-local h exchange (512-thread blocks are dead: allocator pins them at
// 128 VGPR, R7/R8). Geometry: 8 bg x 8 batches, 64 cg -> 512 blocks x 256
// threads, 2 blocks/CU. bg = blockIdx&7 = expected XCD (m09 round-robin).
//  - Producers dual-store h: plain store -> own XCD L2 (loc) + agent store
//    -> LIC (lic). Consumers poll loc with sc0 loads (L1-bypass, L2-served,
//    ~200cyc RT, zero LIC traffic); timeout => per-fragment LIC fallback.
//    Correctness never depends on XCD assignment, only speed.
//  - Salted tags (salt bumped by cvt_x in device mem each dispatch,
//    graph-capture-safe; bit15 set so memset zeros never validate) kill
//    cross-dispatch stale-dirty-L2 false-valids. t=0 skips poll (h0=0).
//  - Register diet for 2 blocks/CU: poll 8 frags as 4+4 (q 64->32 regs),
//    X prefetch depth t+1 only, wih iter-16 one-frag-per-wave.
//  - MFMA B-tiles half-filled (8 batches): lanes c16>=8 carry garbage that
//    lands only in unread gates_s columns.

#define B_  64
#define S_  512
#define D_  544
#define H_  1024
#define NBG 8
#define NCG 64
#define GRID_ (NBG*NCG)
#define THR_ 256
#define LB_ROUNDS 512

typedef __attribute__((ext_vector_type(8))) short bf16x8;
typedef __attribute__((ext_vector_type(4))) float f32x4;
typedef unsigned long long u64;

__device__ inline ushort f2b(float x){
  unsigned u = __float_as_uint(x);
  u = (u + 0x7FFFu + ((u >> 16) & 1u)) >> 16;   // RNE
  return (ushort)u;
}

__device__ inline bf16x8 pack8(float4 a, float4 b){
  bf16x8 r;
  r[0]=(short)f2b(a.x); r[1]=(short)f2b(a.y); r[2]=(short)f2b(a.z); r[3]=(short)f2b(a.w);
  r[4]=(short)f2b(b.x); r[5]=(short)f2b(b.y); r[6]=(short)f2b(b.z); r[7]=(short)f2b(b.w);
  return r;
}

__device__ inline u64 ld64a(const u64* q){
  return __hip_atomic_load(q, __ATOMIC_RELAXED, __HIP_MEMORY_SCOPE_AGENT);
}

__device__ inline float sigm(float x){ return __builtin_amdgcn_rcpf(1.f + __expf(-x)); }
__device__ inline float tanh_(float x){ return 1.f - 2.f*__builtin_amdgcn_rcpf(1.f + __expf(2.f*x)); }

// 32B tagged-fragment load, L2 scope: sc0 bypasses L1, served by own-XCD L2.
template<int O>
__device__ __forceinline__ void frag_l2(u64& a, u64& b, u64& c, u64& d, const void* p){
  asm volatile(
    "global_load_dwordx2 %0, %4, off offset:%c5 sc0\n\t"
    "global_load_dwordx2 %1, %4, off offset:%c6 sc0\n\t"
    "global_load_dwordx2 %2, %4, off offset:%c7 sc0\n\t"
    "global_load_dwordx2 %3, %4, off offset:%c8 sc0"
    : "=&v"(a), "=&v"(b), "=&v"(c), "=&v"(d)
    : "v"(p), "n"(O), "n"(O+8), "n"(O+16), "n"(O+24)
    : "memory");
}
__device__ __forceinline__ void waitv(){
  asm volatile("s_waitcnt vmcnt(0)" ::: "memory");
  __builtin_amdgcn_sched_barrier(0);   // rule #18: block VALU hoist past the wait
}

__global__ void cvt_x(const float* __restrict__ x, ushort* __restrict__ xb, int n4,
                      unsigned* salt_ctr){
  if (blockIdx.x == 0 && threadIdx.x == 0)
    atomicAdd(salt_ctr, 1024u);        // new salt per dispatch (device-side state)
  int i = blockIdx.x*256 + threadIdx.x;
  if (i >= n4) return;
  float4 v = ((const float4*)x)[i];
  ushort4 o;
  o.x=f2b(v.x); o.y=f2b(v.y); o.z=f2b(v.z); o.w=f2b(v.w);
  ((ushort4*)xb)[i] = o;
}

// Poll+consume one half (4 fragments) of this lane's h slab slice.
template<int H>
__device__ __forceinline__ void poll_half(
    const char* lbase, const u64* gp, u64 texp, u64 tmask,
    int& use_loc, int t, int c16,
    const bf16x8 (&whhf)[4][8], f32x4 (&acc)[4])
{
  u64 q[4][4];
  if (c16 < 8){
    unsigned stale = 0xfu;
    if (use_loc){
      frag_l2<(H*4+0)*128>(q[0][0],q[0][1],q[0][2],q[0][3], lbase);
      frag_l2<(H*4+1)*128>(q[1][0],q[1][1],q[1][2],q[1][3], lbase);
      frag_l2<(H*4+2)*128>(q[2][0],q[2][1],q[2][2],q[2][3], lbase);
      frag_l2<(H*4+3)*128>(q[3][0],q[3][1],q[3][2],q[3][3], lbase);
      waitv();
      int rounds = 0;
      for(;;){
        unsigned ns = 0;
        #pragma unroll
        for (int f = 0; f < 4; ++f)
          if (stale & (1u<<f)){
            u64 d = ((q[f][0]^texp)|(q[f][1]^texp)|(q[f][2]^texp)|(q[f][3]^texp)) & tmask;
            if (d) ns |= (1u<<f);
          }
        stale = ns;
        if (!ns) break;
        if (++rounds > LB_ROUNDS){ if (t >= 8) use_loc = 0; break; }
        if (ns & 1u) frag_l2<(H*4+0)*128>(q[0][0],q[0][1],q[0][2],q[0][3], lbase);
        if (ns & 2u) frag_l2<(H*4+1)*128>(q[1][0],q[1][1],q[1][2],q[1][3], lbase);
        if (ns & 4u) frag_l2<(H*4+2)*128>(q[2][0],q[2][1],q[2][2],q[2][3], lbase);
        if (ns & 8u) frag_l2<(H*4+3)*128>(q[3][0],q[3][1],q[3][2],q[3][3], lbase);
        waitv();
      }
    }
    if (stale){                           // LIC backbone (correctness path)
      #pragma unroll
      for (int f = 0; f < 4; ++f)
        if (stale & (1u<<f)){
          const u64* p = gp + (H*4+f)*16;
          q[f][0]=ld64a(p); q[f][1]=ld64a(p+1); q[f][2]=ld64a(p+2); q[f][3]=ld64a(p+3);
        }
      long rr = 0;
      while (stale){
        unsigned ns = 0;
        #pragma unroll
        for (int f = 0; f < 4; ++f)
          if (stale & (1u<<f)){
            u64 d = ((q[f][0]^texp)|(q[f][1]^texp)|(q[f][2]^texp)|(q[f][3]^texp)) & tmask;
            if (d){
              const u64* p = gp + (H*4+f)*16;
              q[f][0]=ld64a(p); q[f][1]=ld64a(p+1); q[f][2]=ld64a(p+2); q[f][3]=ld64a(p+3);
              ns |= (1u<<f);
            }
          }
        stale = ns;
        if (++rr > (1L<<20)) break;       // never hang the harness
      }
    }
  } else {
    #pragma unroll
    for (int f = 0; f < 4; ++f){ q[f][0]=0; q[f][1]=0; q[f][2]=0; q[f][3]=0; }
  }
  // extract bf16 payloads + hh MFMA
  #pragma unroll
  for (int f = 0; f < 4; ++f){
    union { unsigned u[4]; bf16x8 v8; } eb;
    #pragma unroll
    for (int w = 0; w < 4; ++w){
      unsigned lo = (unsigned)q[f][w], hi = (unsigned)(q[f][w] >> 32);
      eb.u[w] = (lo & 0xffffu) | (hi << 16);
    }
    #pragma unroll
    for (int mt = 0; mt < 4; ++mt)
      acc[mt] = __builtin_amdgcn_mfma_f32_16x16x32_bf16(whhf[mt][H*4+f], eb.v8, acc[mt], 0,0,0);
  }
}

__global__ __launch_bounds__(THR_,2) void lstm_persist(
    const float* __restrict__ Wih, const float* __restrict__ Whh,
    const float* __restrict__ bih, const float* __restrict__ bhh,
    const ushort* __restrict__ Xb,
    unsigned* lic, unsigned* loc, const unsigned* salt_ctr,
    float* __restrict__ out)
{
  const int tid  = threadIdx.x;
  const int wave = tid >> 6;          // K-quarter of H
  const int lane = tid & 63;
  const int c16  = lane & 15;         // batch col in MFMA tile (0..7 real)
  const int quad = lane >> 4;
  const int bg   = blockIdx.x & 7;    // expected XCD
  const int cg   = blockIdx.x >> 3;   // 0..63

  __shared__ float gates_s[2][4][64][17];

  const unsigned salt = __hip_atomic_load(salt_ctr, __ATOMIC_RELAXED, __HIP_MEMORY_SCOPE_AGENT);

  // ---- W_hh fragments: 4 gates x 8 K-iters (128 VGPR) ----
  bf16x8 whhf[4][8];
  #pragma unroll
  for (int mt = 0; mt < 4; ++mt){
    const size_t grow = (size_t)(mt*H_ + cg*16 + c16);
    #pragma unroll
    for (int i = 0; i < 8; ++i){
      int k = wave*256 + i*32 + quad*8;
      const float4* p = (const float4*)(Whh + grow*H_ + k);
      whhf[mt][i] = pack8(p[0], p[1]);
    }
  }
  // ---- W_ih fragments: it = wave+4*ii (ii<4, it<16); it=16 -> mt=wave only ----
  bf16x8 wihf[4][4];
  #pragma unroll
  for (int mt = 0; mt < 4; ++mt){
    const size_t grow = (size_t)(mt*H_ + cg*16 + c16);
    #pragma unroll
    for (int ii = 0; ii < 4; ++ii){
      int k = (wave + 4*ii)*32 + quad*8;
      const float4* p = (const float4*)(Wih + grow*D_ + k);
      wihf[mt][ii] = pack8(p[0], p[1]);
    }
  }
  bf16x8 wihf16;
  {
    const size_t grow = (size_t)(wave*H_ + cg*16 + c16);
    const float4* p = (const float4*)(Wih + grow*D_ + 512 + quad*8);
    wihf16 = pack8(p[0], p[1]);
  }

  // ---- update mapping: thread owns (batch nn<8, col uu) ----
  const int uu = tid & 15;
  const int nn = tid >> 4;
  float bsum[4];
  #pragma unroll
  for (int g = 0; g < 4; ++g)
    bsum[g] = bih[g*H_ + cg*16 + uu] + bhh[g*H_ + cg*16 + uu];
  float cstate = 0.f;
  int use_loc = 1;

  f32x4 acc[4];
  bf16x8 xraw[4]; bf16x8 xraw16;

  auto zacc = [&]{
    #pragma unroll
    for (int mt = 0; mt < 4; ++mt) acc[mt] = (f32x4){0.f,0.f,0.f,0.f};
  };
  auto ldx = [&](int t2){
    const ushort* xrow = Xb + ((size_t)(bg*8 + (c16 & 7))*S_ + t2)*D_;
    #pragma unroll
    for (int ii = 0; ii < 4; ++ii)
      xraw[ii] = *(const bf16x8*)(xrow + (wave + 4*ii)*32 + quad*8);
    xraw16 = *(const bf16x8*)(xrow + 512 + quad*8);
  };
  auto xp_mfma = [&]{
    #pragma unroll
    for (int ii = 0; ii < 4; ++ii)
      #pragma unroll
      for (int mt = 0; mt < 4; ++mt)
        acc[mt] = __builtin_amdgcn_mfma_f32_16x16x32_bf16(wihf[mt][ii], xraw[ii], acc[mt], 0,0,0);
    if      (wave==0) acc[0] = __builtin_amdgcn_mfma_f32_16x16x32_bf16(wihf16, xraw16, acc[0], 0,0,0);
    else if (wave==1) acc[1] = __builtin_amdgcn_mfma_f32_16x16x32_bf16(wihf16, xraw16, acc[1], 0,0,0);
    else if (wave==2) acc[2] = __builtin_amdgcn_mfma_f32_16x16x32_bf16(wihf16, xraw16, acc[2], 0,0,0);
    else              acc[3] = __builtin_amdgcn_mfma_f32_16x16x32_bf16(wihf16, xraw16, acc[3], 0,0,0);
  };

  // consumer slab slice (words): frag i covers k = wave*256 + i*32 + quad*8, batch c16
  const size_t pbase = (size_t)bg*8192 + (size_t)c16*1024 + wave*256 + quad*8;
  const u64 tmask = 0xffff0000ffff0000ull;

  // prologue: acc = xp(0); h(0)=0 so t=0 needs no poll / no hh MFMA
  ldx(0);
  zacc();
  xp_mfma();

  for (int t = 0; t < S_; ++t){
    const unsigned* licp = lic + (t & 1)*(B_*H_);
    unsigned*       licn = lic + ((t & 1)^1)*(B_*H_);
    const unsigned* locp = loc + (t & 1)*(B_*H_);
    unsigned*       locn = loc + ((t & 1)^1)*(B_*H_);
    const unsigned tg = ((salt + (unsigned)t) & 0x7fffu) | 0x8000u;
    const u64 texp = ((u64)tg << 16) | ((u64)tg << 48);
    const char* lbase = (const char*)(locp + pbase);
    const u64*  gp    = (const u64*)licp + (pbase >> 1);

    if (t){
      poll_half<0>(lbase, gp, texp, tmask, use_loc, t, c16, whhf, acc);
      poll_half<1>(lbase, gp, texp, tmask, use_loc, t, c16, whhf, acc);
    }

    // per-wave partials -> LDS (ping-pong, single barrier per step)
    #pragma unroll
    for (int mt = 0; mt < 4; ++mt)
      #pragma unroll
      for (int r = 0; r < 4; ++r)
        gates_s[t & 1][wave][mt*16 + quad*4 + r][c16] = acc[mt][r];
    __syncthreads();

    // update: X(t+1) loads fly under the gate math
    if (t < S_-1) ldx(t+1);
    float gs[4];
    #pragma unroll
    for (int g = 0; g < 4; ++g){
      float s = bsum[g];
      #pragma unroll
      for (int q2 = 0; q2 < 4; ++q2) s += gates_s[t & 1][q2][g*16 + uu][nn];
      gs[g] = s;
    }
    float iv = sigm(gs[0]), fv = sigm(gs[1]), gv = tanh_(gs[2]), ov = sigm(gs[3]);
    float cn = fv*cstate + iv*gv;
    cstate = cn;
    float hv = ov*tanh_(cn);
    if (nn < 8){
      const unsigned tgn = ((salt + (unsigned)(t+1)) & 0x7fffu) | 0x8000u;
      unsigned word = (tgn << 16) | (unsigned)f2b(hv);
      size_t idx = (size_t)bg*8192 + (size_t)nn*1024 + cg*16 + uu;
      __hip_atomic_store(locn + idx, word, __ATOMIC_RELAXED, __HIP_MEMORY_SCOPE_WORKGROUP); // plain -> own L2
      __hip_atomic_store(licn + idx, word, __ATOMIC_RELAXED, __HIP_MEMORY_SCOPE_AGENT);     // LIC backbone
      if (t == S_-1){
        out[(bg*8 + nn)*H_ + cg*16 + uu]          = hv;   // h_n
        out[B_*H_ + (bg*8 + nn)*H_ + cg*16 + uu]  = cn;   // c_n
      }
    }
    if (t < S_-1){
      zacc();
      xp_mfma();     // xp(t+1) ready before poll(t+1)
    }
  }
}

extern "C" void kernel_launch(void* const* d_in, const int* in_sizes, int n_in,
                              void* d_out, int out_size, void* d_ws, size_t ws_size,
                              hipStream_t stream) {
  const float* X   = (const float*)d_in[0];
  const float* Wih = (const float*)d_in[1];
  const float* Whh = (const float*)d_in[2];
  const float* bih = (const float*)d_in[3];
  const float* bhh = (const float*)d_in[4];
  float* out = (float*)d_out;

  // ws: [0,512K) lic dbuf | [512K,1M) loc dbuf | [1M,+4) salt | [1M+256, ...) X bf16
  char* ws = (char*)d_ws;
  const size_t HB       = 2ull * B_ * H_ * sizeof(unsigned);        // 512 KB per exchange buf
  const size_t LOC_OFF  = HB;
  const size_t SALT_OFF = 2*HB;
  const size_t XB_OFF   = 2*HB + 256;
  const size_t XB_BYTES = (size_t)B_ * S_ * D_ * sizeof(ushort);    // 35.65 MB
  if (ws_size < XB_OFF + XB_BYTES) return;  // insufficient scratch: fail visibly

  unsigned* lic   = (unsigned*)ws;
  unsigned* loc   = (unsigned*)(ws + LOC_OFF);
  unsigned* salt  = (unsigned*)(ws + SALT_OFF);
  ushort*   Xb    = (ushort*)(ws + XB_OFF);

  hipMemsetAsync(d_ws, 0, 2*HB, stream);   // zero both exchange bufs (salt NOT cleared)

  int n4 = B_*S_*D_/4;
  cvt_x<<<(n4 + 255)/256, 256, 0, stream>>>(X, Xb, n4, salt);
  lstm_persist<<<GRID_, THR_, 0, stream>>>(Wih, Whh, bih, bhh, Xb, lic, loc, salt, out);
}